// Round 2
// baseline (1001.330 us; speedup 1.0000x reference)
//
#include <hip/hip_runtime.h>
#include <stdint.h>

#define E_NUM 8
#define CAP 8192
#define NTOK 32768
#define CDIM 384
#define DFF 1536

typedef unsigned short u16;
typedef __attribute__((ext_vector_type(8))) short short8;
typedef __attribute__((ext_vector_type(4))) float f32x4;

__device__ inline u16 f2bf(float f) {
    uint32_t u = __builtin_bit_cast(uint32_t, f);
    u += 0x7fffu + ((u >> 16) & 1u);
    return (u16)(u >> 16);
}

__device__ inline void gload_lds16(const void* g, void* l) {
    __builtin_amdgcn_global_load_lds(
        (const __attribute__((address_space(1))) void*)(uintptr_t)g,
        (__attribute__((address_space(3))) void*)(uint32_t)(uintptr_t)l,
        16, 0, 0);
}

// ---------------- routing: 16 tokens/block, w in LDS (transposed) ----------------
// R1 post-mortem: per-lane global gathers of w (stride 32B across lanes) splintered
// into ~32 L1 transactions per load -> 389us. LDS-staged [e][c] layout gives
// stride-1 ds_read (2 lanes/bank = free).
__global__ __launch_bounds__(256) void routing_kernel(
    const float* __restrict__ x, const float* __restrict__ noise,
    const float* __restrict__ w_route, const float* __restrict__ b_route,
    const float* __restrict__ w_noise, const float* __restrict__ b_noise,
    int* __restrict__ cnt, int* __restrict__ list, float* __restrict__ gate)
{
    __shared__ float ws_r[E_NUM * CDIM];
    __shared__ float ws_n[E_NUM * CDIM];
    for (int idx = threadIdx.x; idx < E_NUM * CDIM; idx += 256) {
        int c = idx >> 3, e = idx & 7;          // w layout: (C, E)
        ws_r[e * CDIM + c] = w_route[idx];
        ws_n[e * CDIM + c] = w_noise[idx];
    }
    __syncthreads();

    int w = threadIdx.x >> 6, lane = threadIdx.x & 63;
    int tbase = blockIdx.x * 16 + w * 4;
#pragma unroll
    for (int tt = 0; tt < 4; ++tt) {
        int t = tbase + tt;
        const float* xr = x + (size_t)t * CDIM;
        float xv[CDIM / 64];
#pragma unroll
        for (int i = 0; i < CDIM / 64; ++i) xv[i] = xr[lane + i * 64];
        float ar[E_NUM], an[E_NUM];
#pragma unroll
        for (int e = 0; e < E_NUM; ++e) { ar[e] = 0.f; an[e] = 0.f; }
#pragma unroll
        for (int i = 0; i < CDIM / 64; ++i) {
            int c = lane + i * 64;
#pragma unroll
            for (int e = 0; e < E_NUM; ++e) {
                ar[e] += xv[i] * ws_r[e * CDIM + c];
                an[e] += xv[i] * ws_n[e * CDIM + c];
            }
        }
#pragma unroll
        for (int e = 0; e < E_NUM; ++e) {
#pragma unroll
            for (int off = 32; off > 0; off >>= 1) {
                ar[e] += __shfl_xor(ar[e], off);
                an[e] += __shfl_xor(an[e], off);
            }
        }
        if (lane == 0) {
            float nz[E_NUM];
#pragma unroll
            for (int e = 0; e < E_NUM; ++e) {
                float lg = ar[e] + b_route[e];
                float nl = an[e] + b_noise[e];
                float sp = fmaxf(nl, 0.f) + log1pf(expf(-fabsf(nl)));  // stable softplus
                nz[e] = lg + noise[(size_t)t * E_NUM + e] * sp;
            }
            float v1 = -1e30f; int i1 = 0;
#pragma unroll
            for (int e = 0; e < E_NUM; ++e) if (nz[e] > v1) { v1 = nz[e]; i1 = e; }
            float v2 = -1e30f;
#pragma unroll
            for (int e = 0; e < E_NUM; ++e) if (e != i1 && nz[e] > v2) v2 = nz[e];
            float g = 1.f / (1.f + expf(v2 - v1));
            gate[t] = g;
            int pos = atomicAdd(&cnt[i1], 1);
            if (pos < CAP) list[i1 * CAP + pos] = t;
        }
    }
}

// ------------- transpose + fp32->bf16 convert: in (R,S) -> out (S,R) -------------
__global__ __launch_bounds__(256) void transpose_cvt_kernel(
    const float* __restrict__ in, u16* __restrict__ out, int R, int S)
{
    __shared__ float tile[32][33];
    size_t eoff = (size_t)blockIdx.z * R * S;
    const float* ip = in + eoff;
    u16* op = out + eoff;
    int c0 = blockIdx.x * 32, r0 = blockIdx.y * 32;
    int tx = threadIdx.x, ty = threadIdx.y;
#pragma unroll
    for (int i = ty; i < 32; i += 8)
        tile[i][tx] = ip[(size_t)(r0 + i) * S + (c0 + tx)];
    __syncthreads();
#pragma unroll
    for (int i = ty; i < 32; i += 8)
        op[(size_t)(c0 + i) * R + (r0 + tx)] = f2bf(tile[tx][i]);
}

// ------------- gather x rows -> bf16, zero-pad to 128 boundary -------------
__global__ __launch_bounds__(256) void gather_kernel(
    const float* __restrict__ x, const int* __restrict__ list,
    const int* __restrict__ cnt, u16* __restrict__ Xg,
    int list_stride, int cnt_stride, size_t xg_stride)
{
    int e = blockIdx.z;
    const int* le = list + (size_t)e * list_stride;
    int n = min(cnt[e * cnt_stride], CAP);
    u16* xg = Xg + (size_t)e * xg_stride;
    int w = threadIdx.x >> 6, lane = threadIdx.x & 63;
    int row = blockIdx.x * 4 + w;
    int pad = (n + 127) & ~127;
    if (row >= pad) return;
    u16* orow = xg + (size_t)row * CDIM;
    if (row < n) {
        const float* xr = x + (size_t)le[row] * CDIM;
#pragma unroll
        for (int i = 0; i < CDIM / 64; ++i) orow[lane + i * 64] = f2bf(xr[lane + i * 64]);
    } else {
#pragma unroll
        for (int i = 0; i < CDIM / 64; ++i) orow[lane + i * 64] = 0;
    }
}

// ------------- bf16 MFMA GEMM, 128x128 tile, m97 structure -------------
// A: M x KD bf16 row-major (lda=KD). Bt: ND x KD bf16 row-major (B transposed).
// FFN1: H[row*ND+col] = bf16(relu(acc+b1[col])^2)
// FFN2: Out[tok*CDIM+col] = (acc+b2[col]) * gate[tok], tok = list[row]
template <int KD, int ND, bool FFN1>
__global__ __launch_bounds__(256) void gemm_kernel(
    const u16* __restrict__ A, size_t a_estride,
    const u16* __restrict__ Bt, size_t b_estride,
    const float* __restrict__ bias, int bias_estride,
    u16* __restrict__ H, size_t h_estride,
    float* __restrict__ Out,
    const int* __restrict__ cnt, int cnt_stride,
    const int* __restrict__ list, int list_stride,
    const float* __restrict__ gate)
{
    int e = blockIdx.z;
    int n_e = min(cnt[e * cnt_stride], CAP);
    int m0 = blockIdx.y * 128;
    if (m0 >= n_e) return;
    const u16* Ae = A + (size_t)e * a_estride;
    const u16* Be = Bt + (size_t)e * b_estride;

    __shared__ __align__(16) u16 As[128 * 32];
    __shared__ __align__(16) u16 Bs[128 * 32];

    int tid = threadIdx.x;
    int w = tid >> 6, lane = tid & 63;
    int quad = lane >> 4, l15 = lane & 15;
    int wr = w & 1, wc = w >> 1;
    int n0 = blockIdx.x * 128;

    f32x4 acc[4][4];
    f32x4 zero = {0.f, 0.f, 0.f, 0.f};
#pragma unroll
    for (int a = 0; a < 4; ++a)
#pragma unroll
        for (int b = 0; b < 4; ++b) acc[a][b] = zero;

    for (int kb = 0; kb < KD / 32; ++kb) {
#pragma unroll
        for (int i = 0; i < 2; ++i) {
            int sb = i * 256 + w * 64;
            int sl = sb + lane;
            int row = sl >> 2, ks = sl & 3;
            gload_lds16(Ae + (size_t)(m0 + row) * KD + kb * 32 + ks * 8, &As[sb * 8]);
            gload_lds16(Be + (size_t)(n0 + row) * KD + kb * 32 + ks * 8, &Bs[sb * 8]);
        }
        __syncthreads();
        short8 af[4], bf[4];
#pragma unroll
        for (int t = 0; t < 4; ++t) {
            af[t] = *(const short8*)&As[(wr * 64 + t * 16 + l15) * 32 + quad * 8];
            bf[t] = *(const short8*)&Bs[(wc * 64 + t * 16 + l15) * 32 + quad * 8];
        }
#pragma unroll
        for (int mt = 0; mt < 4; ++mt)
#pragma unroll
            for (int nt = 0; nt < 4; ++nt)
                acc[mt][nt] = __builtin_amdgcn_mfma_f32_16x16x32_bf16(
                    af[mt], bf[nt], acc[mt][nt], 0, 0, 0);
        __syncthreads();
    }

    if (FFN1) {
        u16* He = H + (size_t)e * h_estride;
#pragma unroll
        for (int mt = 0; mt < 4; ++mt) {
            int row = m0 + wr * 64 + mt * 16 + quad * 4;
#pragma unroll
            for (int nt = 0; nt < 4; ++nt) {
                int col = n0 + wc * 64 + nt * 16 + l15;
                float b = bias[e * bias_estride + col];
#pragma unroll
                for (int r = 0; r < 4; ++r) {
                    float v = acc[mt][nt][r] + b;
                    v = fmaxf(v, 0.f);
                    v = v * v;
                    He[(size_t)(row + r) * ND + col] = f2bf(v);
                }
            }
        }
    } else {
#pragma unroll
        for (int mt = 0; mt < 4; ++mt) {
            int row = m0 + wr * 64 + mt * 16 + quad * 4;
#pragma unroll
            for (int r = 0; r < 4; ++r) {
                int rr = row + r;
                if (rr < n_e) {
                    int tok = list[e * list_stride + rr];
                    float g = gate[tok];
#pragma unroll
                    for (int nt = 0; nt < 4; ++nt) {
                        int col = n0 + wc * 64 + nt * 16 + l15;
                        float v = acc[mt][nt][r] + bias[e * bias_estride + col];
                        Out[(size_t)tok * CDIM + col] = v * g;
                    }
                }
            }
        }
    }
}

extern "C" void kernel_launch(void* const* d_in, const int* in_sizes, int n_in,
                              void* d_out, int out_size, void* d_ws, size_t ws_size,
                              hipStream_t stream)
{
    const float* x       = (const float*)d_in[0];
    const float* noise   = (const float*)d_in[1];
    const float* w_route = (const float*)d_in[2];
    const float* b_route = (const float*)d_in[3];
    const float* w_noise = (const float*)d_in[4];
    const float* b_noise = (const float*)d_in[5];
    const float* w1      = (const float*)d_in[6];
    const float* b1      = (const float*)d_in[7];
    const float* w2      = (const float*)d_in[8];
    const float* b2      = (const float*)d_in[9];
    float* out = (float*)d_out;

    char* ws = (char*)d_ws;
    size_t off = 0;
    auto alloc = [&](size_t bytes) {
        char* p = ws + off;
        off += (bytes + 255) & ~(size_t)255;
        return p;
    };
    int*   cnt  = (int*)alloc(E_NUM * sizeof(int));
    int*   list = (int*)alloc((size_t)E_NUM * CAP * sizeof(int));
    float* gate = (float*)alloc((size_t)NTOK * sizeof(float));
    u16*   W1t  = (u16*)alloc((size_t)E_NUM * DFF * CDIM * 2);
    u16*   W2t  = (u16*)alloc((size_t)E_NUM * CDIM * DFF * 2);

    size_t xg_full = (size_t)E_NUM * CAP * CDIM * 2;
    size_t h_full  = (size_t)E_NUM * CAP * DFF * 2;
    size_t xg_one  = (size_t)CAP * CDIM * 2;
    size_t h_one   = (size_t)CAP * DFF * 2;
    bool full = (ws_size > off) && (ws_size - off >= xg_full + h_full + 1024);

    hipMemsetAsync(cnt, 0, E_NUM * sizeof(int), stream);
    hipMemsetAsync(d_out, 0, (size_t)out_size * sizeof(float), stream);

    routing_kernel<<<NTOK / 16, 256, 0, stream>>>(x, noise, w_route, b_route,
                                                  w_noise, b_noise, cnt, list, gate);
    // w1[e]: (C, DFF) -> W1t[e]: (DFF, C)
    transpose_cvt_kernel<<<dim3(DFF / 32, CDIM / 32, E_NUM), dim3(32, 8), 0, stream>>>(
        w1, W1t, CDIM, DFF);
    // w2[e]: (DFF, C) -> W2t[e]: (C, DFF)
    transpose_cvt_kernel<<<dim3(CDIM / 32, DFF / 32, E_NUM), dim3(32, 8), 0, stream>>>(
        w2, W2t, DFF, CDIM);

    if (full) {
        u16* Xg = (u16*)alloc(xg_full);
        u16* Hb = (u16*)alloc(h_full);
        gather_kernel<<<dim3(CAP / 4, 1, E_NUM), 256, 0, stream>>>(
            x, list, cnt, Xg, CAP, 1, (size_t)CAP * CDIM);
        gemm_kernel<CDIM, DFF, true><<<dim3(DFF / 128, CAP / 128, E_NUM), 256, 0, stream>>>(
            Xg, (size_t)CAP * CDIM, W1t, (size_t)DFF * CDIM, b1, DFF,
            Hb, (size_t)CAP * DFF, nullptr, cnt, 1, nullptr, 0, nullptr);
        gemm_kernel<DFF, CDIM, false><<<dim3(CDIM / 128, CAP / 128, E_NUM), 256, 0, stream>>>(
            Hb, (size_t)CAP * DFF, W2t, (size_t)CDIM * DFF, b2, CDIM,
            nullptr, 0, out, cnt, 1, list, CAP, gate);
    } else {
        u16* Xg = (u16*)alloc(xg_one);
        u16* Hb = (u16*)alloc(h_one);
        for (int e = 0; e < E_NUM; ++e) {
            gather_kernel<<<dim3(CAP / 4, 1, 1), 256, 0, stream>>>(
                x, list + (size_t)e * CAP, cnt + e, Xg, 0, 0, 0);
            gemm_kernel<CDIM, DFF, true><<<dim3(DFF / 128, CAP / 128, 1), 256, 0, stream>>>(
                Xg, 0, W1t + (size_t)e * DFF * CDIM, 0, b1 + (size_t)e * DFF, 0,
                Hb, 0, nullptr, cnt + e, 0, nullptr, 0, nullptr);
            gemm_kernel<DFF, CDIM, false><<<dim3(CDIM / 128, CAP / 128, 1), 256, 0, stream>>>(
                Hb, 0, W2t + (size_t)e * CDIM * DFF, 0, b2 + (size_t)e * CDIM, 0,
                nullptr, 0, out, cnt + e, 0, list + (size_t)e * CAP, 0, gate);
        }
    }
}

// Round 3
// 680.832 us; speedup vs baseline: 1.4707x; 1.4707x over previous
//
#include <hip/hip_runtime.h>
#include <stdint.h>

#define E_NUM 8
#define CAP 8192
#define NTOK 32768
#define CDIM 384
#define DFF 1536
#define CNT_PAD 64  // ints between counters -> 256B, separate cache lines

typedef unsigned short u16;
typedef __attribute__((ext_vector_type(8))) short short8;
typedef __attribute__((ext_vector_type(4))) float f32x4;

__device__ inline u16 f2bf(float f) {
    uint32_t u = __builtin_bit_cast(uint32_t, f);
    u += 0x7fffu + ((u >> 16) & 1u);
    return (u16)(u >> 16);
}

__device__ inline void gload_lds16(const void* g, void* l) {
    __builtin_amdgcn_global_load_lds(
        (const __attribute__((address_space(1))) void*)(uintptr_t)g,
        (__attribute__((address_space(3))) void*)(uint32_t)(uintptr_t)l,
        16, 0, 0);
}

// ---------------- routing phase 1: logits/top1/gate, NO atomics ----------------
// R2 post-mortem: 32768 same-cacheline atomicAdds serialized ~30cyc each = ~400us.
// This kernel now only computes; list-building moved to ballot-aggregated phase 2.
__global__ __launch_bounds__(256) void routing_kernel(
    const float* __restrict__ x, const float* __restrict__ noise,
    const float* __restrict__ w_route, const float* __restrict__ b_route,
    const float* __restrict__ w_noise, const float* __restrict__ b_noise,
    int* __restrict__ top1, float* __restrict__ gate)
{
    __shared__ float ws_r[E_NUM * CDIM];
    __shared__ float ws_n[E_NUM * CDIM];
    for (int idx = threadIdx.x; idx < E_NUM * CDIM; idx += 256) {
        int c = idx >> 3, e = idx & 7;          // w layout: (C, E)
        ws_r[e * CDIM + c] = w_route[idx];
        ws_n[e * CDIM + c] = w_noise[idx];
    }
    __syncthreads();

    int w = threadIdx.x >> 6, lane = threadIdx.x & 63;
    int tbase = blockIdx.x * 16 + w * 4;
#pragma unroll
    for (int tt = 0; tt < 4; ++tt) {
        int t = tbase + tt;
        const float* xr = x + (size_t)t * CDIM;
        float xv[CDIM / 64];
#pragma unroll
        for (int i = 0; i < CDIM / 64; ++i) xv[i] = xr[lane + i * 64];
        float ar[E_NUM], an[E_NUM];
#pragma unroll
        for (int e = 0; e < E_NUM; ++e) { ar[e] = 0.f; an[e] = 0.f; }
#pragma unroll
        for (int i = 0; i < CDIM / 64; ++i) {
            int c = lane + i * 64;
#pragma unroll
            for (int e = 0; e < E_NUM; ++e) {
                ar[e] += xv[i] * ws_r[e * CDIM + c];
                an[e] += xv[i] * ws_n[e * CDIM + c];
            }
        }
#pragma unroll
        for (int e = 0; e < E_NUM; ++e) {
#pragma unroll
            for (int off = 32; off > 0; off >>= 1) {
                ar[e] += __shfl_xor(ar[e], off);
                an[e] += __shfl_xor(an[e], off);
            }
        }
        if (lane == 0) {
            float nz[E_NUM];
#pragma unroll
            for (int e = 0; e < E_NUM; ++e) {
                float lg = ar[e] + b_route[e];
                float nl = an[e] + b_noise[e];
                float sp = fmaxf(nl, 0.f) + log1pf(expf(-fabsf(nl)));  // stable softplus
                nz[e] = lg + noise[(size_t)t * E_NUM + e] * sp;
            }
            float v1 = -1e30f; int i1 = 0;
#pragma unroll
            for (int e = 0; e < E_NUM; ++e) if (nz[e] > v1) { v1 = nz[e]; i1 = e; }
            float v2 = -1e30f;
#pragma unroll
            for (int e = 0; e < E_NUM; ++e) if (e != i1 && nz[e] > v2) v2 = nz[e];
            gate[t] = 1.f / (1.f + expf(v2 - v1));
            top1[t] = i1;
        }
    }
}

// ---------------- routing phase 2: ballot-aggregated list build ----------------
// One thread per token. Per wave, per expert: one atomicAdd of popcount to a
// cacheline-padded counter; lanes compute their slot via masked-popcount rank.
__global__ __launch_bounds__(256) void build_lists_kernel(
    const int* __restrict__ top1, int* __restrict__ cnt, int* __restrict__ list)
{
    int t = blockIdx.x * 256 + threadIdx.x;
    int lane = threadIdx.x & 63;
    int e1 = top1[t];
#pragma unroll
    for (int e = 0; e < E_NUM; ++e) {
        unsigned long long m = __ballot(e1 == e);
        if (m == 0) continue;  // wave-uniform
        int c = __popcll(m);
        int leader = __ffsll((long long)m) - 1;
        int base = 0;
        if (lane == leader) base = atomicAdd(&cnt[e * CNT_PAD], c);
        base = __shfl(base, leader);
        if (e1 == e) {
            int pos = base + __popcll(m & ((1ull << lane) - 1ull));
            if (pos < CAP) list[e * CAP + pos] = t;
        }
    }
}

// ------------- transpose + fp32->bf16 convert: in (R,S) -> out (S,R) -------------
__global__ __launch_bounds__(256) void transpose_cvt_kernel(
    const float* __restrict__ in, u16* __restrict__ out, int R, int S)
{
    __shared__ float tile[32][33];
    size_t eoff = (size_t)blockIdx.z * R * S;
    const float* ip = in + eoff;
    u16* op = out + eoff;
    int c0 = blockIdx.x * 32, r0 = blockIdx.y * 32;
    int tx = threadIdx.x, ty = threadIdx.y;
#pragma unroll
    for (int i = ty; i < 32; i += 8)
        tile[i][tx] = ip[(size_t)(r0 + i) * S + (c0 + tx)];
    __syncthreads();
#pragma unroll
    for (int i = ty; i < 32; i += 8)
        op[(size_t)(c0 + i) * R + (r0 + tx)] = f2bf(tile[tx][i]);
}

// ------------- gather x rows -> bf16, zero-pad to 128 boundary -------------
__global__ __launch_bounds__(256) void gather_kernel(
    const float* __restrict__ x, const int* __restrict__ list,
    const int* __restrict__ cnt, u16* __restrict__ Xg,
    int list_stride, int cnt_stride, size_t xg_stride)
{
    int e = blockIdx.z;
    const int* le = list + (size_t)e * list_stride;
    int n = min(cnt[e * cnt_stride], CAP);
    u16* xg = Xg + (size_t)e * xg_stride;
    int w = threadIdx.x >> 6, lane = threadIdx.x & 63;
    int row = blockIdx.x * 4 + w;
    int pad = (n + 127) & ~127;
    if (row >= pad) return;
    u16* orow = xg + (size_t)row * CDIM;
    if (row < n) {
        const float* xr = x + (size_t)le[row] * CDIM;
#pragma unroll
        for (int i = 0; i < CDIM / 64; ++i) orow[lane + i * 64] = f2bf(xr[lane + i * 64]);
    } else {
#pragma unroll
        for (int i = 0; i < CDIM / 64; ++i) orow[lane + i * 64] = 0;
    }
}

// ------------- bf16 MFMA GEMM, 128x128 tile, m97 structure -------------
// A: M x KD bf16 row-major (lda=KD). Bt: ND x KD bf16 row-major (B transposed).
// FFN1: H[row*ND+col] = bf16(relu(acc+b1[col])^2)
// FFN2: Out[tok*CDIM+col] = (acc+b2[col]) * gate[tok], tok = list[row]
template <int KD, int ND, bool FFN1>
__global__ __launch_bounds__(256) void gemm_kernel(
    const u16* __restrict__ A, size_t a_estride,
    const u16* __restrict__ Bt, size_t b_estride,
    const float* __restrict__ bias, int bias_estride,
    u16* __restrict__ H, size_t h_estride,
    float* __restrict__ Out,
    const int* __restrict__ cnt, int cnt_stride,
    const int* __restrict__ list, int list_stride,
    const float* __restrict__ gate)
{
    int e = blockIdx.z;
    int n_e = min(cnt[e * cnt_stride], CAP);
    int m0 = blockIdx.y * 128;
    if (m0 >= n_e) return;
    const u16* Ae = A + (size_t)e * a_estride;
    const u16* Be = Bt + (size_t)e * b_estride;

    __shared__ __align__(16) u16 As[128 * 32];
    __shared__ __align__(16) u16 Bs[128 * 32];

    int tid = threadIdx.x;
    int w = tid >> 6, lane = tid & 63;
    int quad = lane >> 4, l15 = lane & 15;
    int wr = w & 1, wc = w >> 1;
    int n0 = blockIdx.x * 128;

    f32x4 acc[4][4];
    f32x4 zero = {0.f, 0.f, 0.f, 0.f};
#pragma unroll
    for (int a = 0; a < 4; ++a)
#pragma unroll
        for (int b = 0; b < 4; ++b) acc[a][b] = zero;

    for (int kb = 0; kb < KD / 32; ++kb) {
#pragma unroll
        for (int i = 0; i < 2; ++i) {
            int sb = i * 256 + w * 64;
            int sl = sb + lane;
            int row = sl >> 2, ks = sl & 3;
            gload_lds16(Ae + (size_t)(m0 + row) * KD + kb * 32 + ks * 8, &As[sb * 8]);
            gload_lds16(Be + (size_t)(n0 + row) * KD + kb * 32 + ks * 8, &Bs[sb * 8]);
        }
        __syncthreads();
        short8 af[4], bf[4];
#pragma unroll
        for (int t = 0; t < 4; ++t) {
            af[t] = *(const short8*)&As[(wr * 64 + t * 16 + l15) * 32 + quad * 8];
            bf[t] = *(const short8*)&Bs[(wc * 64 + t * 16 + l15) * 32 + quad * 8];
        }
#pragma unroll
        for (int mt = 0; mt < 4; ++mt)
#pragma unroll
            for (int nt = 0; nt < 4; ++nt)
                acc[mt][nt] = __builtin_amdgcn_mfma_f32_16x16x32_bf16(
                    af[mt], bf[nt], acc[mt][nt], 0, 0, 0);
        __syncthreads();
    }

    if (FFN1) {
        u16* He = H + (size_t)e * h_estride;
#pragma unroll
        for (int mt = 0; mt < 4; ++mt) {
            int row = m0 + wr * 64 + mt * 16 + quad * 4;
#pragma unroll
            for (int nt = 0; nt < 4; ++nt) {
                int col = n0 + wc * 64 + nt * 16 + l15;
                float b = bias[e * bias_estride + col];
#pragma unroll
                for (int r = 0; r < 4; ++r) {
                    float v = acc[mt][nt][r] + b;
                    v = fmaxf(v, 0.f);
                    v = v * v;
                    He[(size_t)(row + r) * ND + col] = f2bf(v);
                }
            }
        }
    } else {
#pragma unroll
        for (int mt = 0; mt < 4; ++mt) {
            int row = m0 + wr * 64 + mt * 16 + quad * 4;
#pragma unroll
            for (int r = 0; r < 4; ++r) {
                int rr = row + r;
                if (rr < n_e) {
                    int tok = list[e * list_stride + rr];
                    float g = gate[tok];
#pragma unroll
                    for (int nt = 0; nt < 4; ++nt) {
                        int col = n0 + wc * 64 + nt * 16 + l15;
                        float v = acc[mt][nt][r] + bias[e * bias_estride + col];
                        Out[(size_t)tok * CDIM + col] = v * g;
                    }
                }
            }
        }
    }
}

extern "C" void kernel_launch(void* const* d_in, const int* in_sizes, int n_in,
                              void* d_out, int out_size, void* d_ws, size_t ws_size,
                              hipStream_t stream)
{
    const float* x       = (const float*)d_in[0];
    const float* noise   = (const float*)d_in[1];
    const float* w_route = (const float*)d_in[2];
    const float* b_route = (const float*)d_in[3];
    const float* w_noise = (const float*)d_in[4];
    const float* b_noise = (const float*)d_in[5];
    const float* w1      = (const float*)d_in[6];
    const float* b1      = (const float*)d_in[7];
    const float* w2      = (const float*)d_in[8];
    const float* b2      = (const float*)d_in[9];
    float* out = (float*)d_out;

    char* ws = (char*)d_ws;
    size_t off = 0;
    auto alloc = [&](size_t bytes) {
        char* p = ws + off;
        off += (bytes + 255) & ~(size_t)255;
        return p;
    };
    int*   cnt  = (int*)alloc((size_t)E_NUM * CNT_PAD * sizeof(int));
    int*   top1 = (int*)alloc((size_t)NTOK * sizeof(int));
    int*   list = (int*)alloc((size_t)E_NUM * CAP * sizeof(int));
    float* gate = (float*)alloc((size_t)NTOK * sizeof(float));
    u16*   W1t  = (u16*)alloc((size_t)E_NUM * DFF * CDIM * 2);
    u16*   W2t  = (u16*)alloc((size_t)E_NUM * CDIM * DFF * 2);

    size_t xg_full = (size_t)E_NUM * CAP * CDIM * 2;
    size_t h_full  = (size_t)E_NUM * CAP * DFF * 2;
    size_t xg_one  = (size_t)CAP * CDIM * 2;
    size_t h_one   = (size_t)CAP * DFF * 2;
    bool full = (ws_size > off) && (ws_size - off >= xg_full + h_full + 1024);

    hipMemsetAsync(cnt, 0, (size_t)E_NUM * CNT_PAD * sizeof(int), stream);
    hipMemsetAsync(d_out, 0, (size_t)out_size * sizeof(float), stream);

    routing_kernel<<<NTOK / 16, 256, 0, stream>>>(x, noise, w_route, b_route,
                                                  w_noise, b_noise, top1, gate);
    build_lists_kernel<<<NTOK / 256, 256, 0, stream>>>(top1, cnt, list);
    // w1[e]: (C, DFF) -> W1t[e]: (DFF, C)
    transpose_cvt_kernel<<<dim3(DFF / 32, CDIM / 32, E_NUM), dim3(32, 8), 0, stream>>>(
        w1, W1t, CDIM, DFF);
    // w2[e]: (DFF, C) -> W2t[e]: (C, DFF)
    transpose_cvt_kernel<<<dim3(CDIM / 32, DFF / 32, E_NUM), dim3(32, 8), 0, stream>>>(
        w2, W2t, DFF, CDIM);

    if (full) {
        u16* Xg = (u16*)alloc(xg_full);
        u16* Hb = (u16*)alloc(h_full);
        gather_kernel<<<dim3(CAP / 4, 1, E_NUM), 256, 0, stream>>>(
            x, list, cnt, Xg, CAP, CNT_PAD, (size_t)CAP * CDIM);
        gemm_kernel<CDIM, DFF, true><<<dim3(DFF / 128, CAP / 128, E_NUM), 256, 0, stream>>>(
            Xg, (size_t)CAP * CDIM, W1t, (size_t)DFF * CDIM, b1, DFF,
            Hb, (size_t)CAP * DFF, nullptr, cnt, CNT_PAD, nullptr, 0, nullptr);
        gemm_kernel<DFF, CDIM, false><<<dim3(CDIM / 128, CAP / 128, E_NUM), 256, 0, stream>>>(
            Hb, (size_t)CAP * DFF, W2t, (size_t)CDIM * DFF, b2, CDIM,
            nullptr, 0, out, cnt, CNT_PAD, list, CAP, gate);
    } else {
        u16* Xg = (u16*)alloc(xg_one);
        u16* Hb = (u16*)alloc(h_one);
        for (int e = 0; e < E_NUM; ++e) {
            gather_kernel<<<dim3(CAP / 4, 1, 1), 256, 0, stream>>>(
                x, list + (size_t)e * CAP, cnt + e * CNT_PAD, Xg, 0, 0, 0);
            gemm_kernel<CDIM, DFF, true><<<dim3(DFF / 128, CAP / 128, 1), 256, 0, stream>>>(
                Xg, 0, W1t + (size_t)e * DFF * CDIM, 0, b1 + (size_t)e * DFF, 0,
                Hb, 0, nullptr, cnt + e * CNT_PAD, 0, nullptr, 0, nullptr);
            gemm_kernel<DFF, CDIM, false><<<dim3(CDIM / 128, CAP / 128, 1), 256, 0, stream>>>(
                Hb, 0, W2t + (size_t)e * CDIM * DFF, 0, b2 + (size_t)e * CDIM, 0,
                nullptr, 0, out, cnt + e * CNT_PAD, 0, list + (size_t)e * CAP, 0, gate);
        }
    }
}

// Round 4
// 421.728 us; speedup vs baseline: 2.3744x; 1.6144x over previous
//
#include <hip/hip_runtime.h>
#include <stdint.h>

#define E_NUM 8
#define CAP 8192
#define NTOK 32768
#define CDIM 384
#define DFF 1536
#define CNT_PAD 64  // ints between counters -> 256B, separate cache lines

typedef unsigned short u16;
typedef __attribute__((ext_vector_type(8))) short short8;
typedef __attribute__((ext_vector_type(4))) float f32x4;

__device__ inline u16 f2bf(float f) {
    uint32_t u = __builtin_bit_cast(uint32_t, f);
    u += 0x7fffu + ((u >> 16) & 1u);
    return (u16)(u >> 16);
}

__device__ inline void gload_lds16(const void* g, void* l) {
    __builtin_amdgcn_global_load_lds(
        (const __attribute__((address_space(1))) void*)(uintptr_t)g,
        (__attribute__((address_space(3))) void*)(uint32_t)(uintptr_t)l,
        16, 0, 0);
}

// DPP row-rotate reduction: after 4 rotate-adds each 16-lane row holds its row
// sum (VALU only, no LDS); one ds_swizzle xor16 folds row pairs; caller finishes
// with readlane(0)+readlane(32).
__device__ inline float rsum_to_halves(float v) {
    int s;
    s = __builtin_bit_cast(int, v);
    v += __builtin_bit_cast(float, __builtin_amdgcn_update_dpp(0, s, 0x121, 0xF, 0xF, false));
    s = __builtin_bit_cast(int, v);
    v += __builtin_bit_cast(float, __builtin_amdgcn_update_dpp(0, s, 0x122, 0xF, 0xF, false));
    s = __builtin_bit_cast(int, v);
    v += __builtin_bit_cast(float, __builtin_amdgcn_update_dpp(0, s, 0x124, 0xF, 0xF, false));
    s = __builtin_bit_cast(int, v);
    v += __builtin_bit_cast(float, __builtin_amdgcn_update_dpp(0, s, 0x128, 0xF, 0xF, false));
    s = __builtin_bit_cast(int, v);
    v += __builtin_bit_cast(float, __builtin_amdgcn_ds_swizzle(s, 0x401F));
    return v;
}

__device__ inline float lane_total(float v) {
    int s = __builtin_bit_cast(int, v);
    return __builtin_bit_cast(float, __builtin_amdgcn_readlane(s, 0)) +
           __builtin_bit_cast(float, __builtin_amdgcn_readlane(s, 32));
}

// ---------------- routing: weights in VGPRs, DPP reduce, no atomics ----------------
// R3 post-mortem: 96 ds_read (w) + 96 ds_swizzle (shfl butterfly) per token made
// routing LDS-pipe bound (82us). Weights now live in 96 VGPRs (coalesced load
// once/block); reduction is DPP rotate-adds + 1 swizzle + 2 readlanes.
__global__ __launch_bounds__(256) void routing_kernel(
    const float* __restrict__ x, const float* __restrict__ noise,
    const float* __restrict__ w_route, const float* __restrict__ b_route,
    const float* __restrict__ w_noise, const float* __restrict__ b_noise,
    int* __restrict__ top1, float* __restrict__ gate)
{
    int lane = threadIdx.x & 63, w = threadIdx.x >> 6;
    // wr[i][e] = w_route[(lane+64i)*8 + e]; 32B/lane contiguous -> coalesced
    float wr[6][8], wn[6][8];
#pragma unroll
    for (int i = 0; i < 6; ++i) {
        const float4* pr = (const float4*)(w_route + (size_t)(lane + 64 * i) * 8);
        const float4* pn = (const float4*)(w_noise + (size_t)(lane + 64 * i) * 8);
        float4 a = pr[0], b = pr[1], c = pn[0], d = pn[1];
        wr[i][0] = a.x; wr[i][1] = a.y; wr[i][2] = a.z; wr[i][3] = a.w;
        wr[i][4] = b.x; wr[i][5] = b.y; wr[i][6] = b.z; wr[i][7] = b.w;
        wn[i][0] = c.x; wn[i][1] = c.y; wn[i][2] = c.z; wn[i][3] = c.w;
        wn[i][4] = d.x; wn[i][5] = d.y; wn[i][6] = d.z; wn[i][7] = d.w;
    }
    float br[E_NUM], bn[E_NUM];
#pragma unroll
    for (int e = 0; e < E_NUM; ++e) { br[e] = b_route[e]; bn[e] = b_noise[e]; }

    int tbase = blockIdx.x * 16 + w * 4;
#pragma unroll
    for (int tt = 0; tt < 4; ++tt) {
        int t = tbase + tt;
        const float* xr = x + (size_t)t * CDIM;
        float xv[6];
#pragma unroll
        for (int i = 0; i < 6; ++i) xv[i] = xr[lane + i * 64];
        float ar[E_NUM], an[E_NUM];
#pragma unroll
        for (int e = 0; e < E_NUM; ++e) { ar[e] = 0.f; an[e] = 0.f; }
#pragma unroll
        for (int i = 0; i < 6; ++i)
#pragma unroll
            for (int e = 0; e < E_NUM; ++e) {
                ar[e] += xv[i] * wr[i][e];
                an[e] += xv[i] * wn[i][e];
            }
        float nz[E_NUM];
        const float* np = noise + (size_t)t * E_NUM;
#pragma unroll
        for (int e = 0; e < E_NUM; ++e) {
            float sr = lane_total(rsum_to_halves(ar[e])) + br[e];
            float sn = lane_total(rsum_to_halves(an[e])) + bn[e];
            float sp = fmaxf(sn, 0.f) + log1pf(expf(-fabsf(sn)));  // stable softplus
            nz[e] = sr + np[e] * sp;  // uniform
        }
        float v1 = -1e30f; int i1 = 0;
#pragma unroll
        for (int e = 0; e < E_NUM; ++e) if (nz[e] > v1) { v1 = nz[e]; i1 = e; }
        float v2 = -1e30f;
#pragma unroll
        for (int e = 0; e < E_NUM; ++e) if (e != i1 && nz[e] > v2) v2 = nz[e];
        if (lane == 0) {
            gate[t] = 1.f / (1.f + expf(v2 - v1));
            top1[t] = i1;
        }
    }
}

// ---------------- ballot-aggregated list build ----------------
__global__ __launch_bounds__(256) void build_lists_kernel(
    const int* __restrict__ top1, int* __restrict__ cnt, int* __restrict__ list)
{
    int t = blockIdx.x * 256 + threadIdx.x;
    int lane = threadIdx.x & 63;
    int e1 = top1[t];
#pragma unroll
    for (int e = 0; e < E_NUM; ++e) {
        unsigned long long m = __ballot(e1 == e);
        if (m == 0) continue;  // wave-uniform
        int c = __popcll(m);
        int leader = __ffsll((long long)m) - 1;
        int base = 0;
        if (lane == leader) base = atomicAdd(&cnt[e * CNT_PAD], c);
        base = __shfl(base, leader);
        if (e1 == e) {
            int pos = base + __popcll(m & ((1ull << lane) - 1ull));
            if (pos < CAP) list[e * CAP + pos] = t;
        }
    }
}

// ---------------- per-round packed-row offsets (device prefix sum) ----------------
__global__ void offsets_kernel(const int* __restrict__ cnt, int* __restrict__ offs,
                               int e0, int re)
{
    if (threadIdx.x == 0 && blockIdx.x == 0) {
        int o = 0;
        for (int j = 0; j < re; ++j) {
            int e = e0 + j;
            offs[e] = o;
            int n = min(cnt[e * CNT_PAD], CAP);
            o += (n + 127) & ~127;
        }
    }
}

// ------------- transpose + fp32->bf16 convert: in (R,S) -> out (S,R) -------------
__global__ __launch_bounds__(256) void transpose_cvt_kernel(
    const float* __restrict__ in, u16* __restrict__ out, int R, int S)
{
    __shared__ float tile[32][33];
    size_t eoff = (size_t)blockIdx.z * R * S;
    const float* ip = in + eoff;
    u16* op = out + eoff;
    int c0 = blockIdx.x * 32, r0 = blockIdx.y * 32;
    int tx = threadIdx.x, ty = threadIdx.y;
#pragma unroll
    for (int i = ty; i < 32; i += 8)
        tile[i][tx] = ip[(size_t)(r0 + i) * S + (c0 + tx)];
    __syncthreads();
#pragma unroll
    for (int i = ty; i < 32; i += 8)
        op[(size_t)(c0 + i) * R + (r0 + tx)] = f2bf(tile[tx][i]);
}

// ------------- gather x rows -> bf16 into packed layout, zero-pad to 128 -------------
__global__ __launch_bounds__(256) void gather_kernel(
    const float* __restrict__ x, const int* __restrict__ list,
    const int* __restrict__ cnt, const int* __restrict__ offs, int e0,
    u16* __restrict__ Xg)
{
    int e = e0 + blockIdx.z;
    const int* le = list + (size_t)e * CAP;
    int n = min(cnt[e * CNT_PAD], CAP);
    int w = threadIdx.x >> 6, lane = threadIdx.x & 63;
    int row = blockIdx.x * 4 + w;
    int pad = (n + 127) & ~127;
    if (row >= pad) return;
    u16* orow = Xg + (size_t)(offs[e] + row) * CDIM;
    if (row < n) {
        const float* xr = x + (size_t)le[row] * CDIM;
#pragma unroll
        for (int i = 0; i < CDIM / 64; ++i) orow[lane + i * 64] = f2bf(xr[lane + i * 64]);
    } else {
#pragma unroll
        for (int i = 0; i < CDIM / 64; ++i) orow[lane + i * 64] = 0;
    }
}

// ------------- bf16 MFMA GEMM, 128x128 tile, packed rows -------------
// A: packed rows x KD bf16. Bt: per-expert ND x KD bf16 (B^T).
// FFN1: H[(offs+row)*ND+col] = bf16(relu(acc+b1)^2)
// FFN2: Out[tok*CDIM+col] = (acc+b2[col]) * gate[tok], tok = list[e*CAP+rr]
template <int KD, int ND, bool FFN1>
__global__ __launch_bounds__(256) void gemm_kernel(
    const u16* __restrict__ A, const u16* __restrict__ Bt,
    const float* __restrict__ bias, u16* __restrict__ H, float* __restrict__ Out,
    const int* __restrict__ cnt, const int* __restrict__ offs, int e0,
    const int* __restrict__ list, const float* __restrict__ gate)
{
    int e = e0 + blockIdx.z;
    int n_e = min(cnt[e * CNT_PAD], CAP);
    int pad_e = (n_e + 127) & ~127;
    int m0 = blockIdx.y * 128;
    if (m0 >= pad_e) return;
    int base = offs[e];
    const u16* Ae = A + (size_t)(base + m0) * KD;
    const u16* Be = Bt + (size_t)e * ND * KD;

    __shared__ __align__(16) u16 As[128 * 32];
    __shared__ __align__(16) u16 Bs[128 * 32];

    int tid = threadIdx.x;
    int w = tid >> 6, lane = tid & 63;
    int quad = lane >> 4, l15 = lane & 15;
    int wr = w & 1, wc = w >> 1;
    int n0 = blockIdx.x * 128;

    f32x4 acc[4][4];
    f32x4 zero = {0.f, 0.f, 0.f, 0.f};
#pragma unroll
    for (int a = 0; a < 4; ++a)
#pragma unroll
        for (int b = 0; b < 4; ++b) acc[a][b] = zero;

    for (int kb = 0; kb < KD / 32; ++kb) {
#pragma unroll
        for (int i = 0; i < 2; ++i) {
            int sb = i * 256 + w * 64;
            int sl = sb + lane;
            int row = sl >> 2, ks = sl & 3;
            gload_lds16(Ae + (size_t)row * KD + kb * 32 + ks * 8, &As[sb * 8]);
            gload_lds16(Be + (size_t)(n0 + row) * KD + kb * 32 + ks * 8, &Bs[sb * 8]);
        }
        __syncthreads();
        short8 af[4], bf[4];
#pragma unroll
        for (int t = 0; t < 4; ++t) {
            af[t] = *(const short8*)&As[(wr * 64 + t * 16 + l15) * 32 + quad * 8];
            bf[t] = *(const short8*)&Bs[(wc * 64 + t * 16 + l15) * 32 + quad * 8];
        }
#pragma unroll
        for (int mt = 0; mt < 4; ++mt)
#pragma unroll
            for (int nt = 0; nt < 4; ++nt)
                acc[mt][nt] = __builtin_amdgcn_mfma_f32_16x16x32_bf16(
                    af[mt], bf[nt], acc[mt][nt], 0, 0, 0);
        __syncthreads();
    }

    if (FFN1) {
        u16* He = H + (size_t)(base + m0) * ND;
#pragma unroll
        for (int mt = 0; mt < 4; ++mt) {
            int rowL = wr * 64 + mt * 16 + quad * 4;
#pragma unroll
            for (int nt = 0; nt < 4; ++nt) {
                int col = n0 + wc * 64 + nt * 16 + l15;
                float b = bias[(size_t)e * ND + col];
#pragma unroll
                for (int r = 0; r < 4; ++r) {
                    float v = acc[mt][nt][r] + b;
                    v = fmaxf(v, 0.f);
                    v = v * v;
                    He[(size_t)(rowL + r) * ND + col] = f2bf(v);
                }
            }
        }
    } else {
#pragma unroll
        for (int mt = 0; mt < 4; ++mt) {
            int rowL = wr * 64 + mt * 16 + quad * 4;
#pragma unroll
            for (int r = 0; r < 4; ++r) {
                int rr = m0 + rowL + r;
                if (rr < n_e) {
                    int tok = list[(size_t)e * CAP + rr];
                    float g = gate[tok];
#pragma unroll
                    for (int nt = 0; nt < 4; ++nt) {
                        int col = n0 + wc * 64 + nt * 16 + l15;
                        float v = acc[mt][nt][r] + bias[(size_t)e * ND + col];
                        Out[(size_t)tok * CDIM + col] = v * g;
                    }
                }
            }
        }
    }
}

extern "C" void kernel_launch(void* const* d_in, const int* in_sizes, int n_in,
                              void* d_out, int out_size, void* d_ws, size_t ws_size,
                              hipStream_t stream)
{
    const float* x       = (const float*)d_in[0];
    const float* noise   = (const float*)d_in[1];
    const float* w_route = (const float*)d_in[2];
    const float* b_route = (const float*)d_in[3];
    const float* w_noise = (const float*)d_in[4];
    const float* b_noise = (const float*)d_in[5];
    const float* w1      = (const float*)d_in[6];
    const float* b1      = (const float*)d_in[7];
    const float* w2      = (const float*)d_in[8];
    const float* b2      = (const float*)d_in[9];
    float* out = (float*)d_out;

    char* ws = (char*)d_ws;
    size_t off = 0;
    auto alloc = [&](size_t bytes) {
        char* p = ws + off;
        off += (bytes + 255) & ~(size_t)255;
        return p;
    };
    int*   cnt  = (int*)alloc((size_t)E_NUM * CNT_PAD * sizeof(int));
    int*   top1 = (int*)alloc((size_t)NTOK * sizeof(int));
    int*   list = (int*)alloc((size_t)E_NUM * CAP * sizeof(int));
    float* gate = (float*)alloc((size_t)NTOK * sizeof(float));
    int*   offs = (int*)alloc((size_t)(E_NUM + 1) * sizeof(int));
    u16*   W1t  = (u16*)alloc((size_t)E_NUM * DFF * CDIM * 2);
    u16*   W2t  = (u16*)alloc((size_t)E_NUM * CDIM * DFF * 2);

    // Packed-row bound: sum_e pad_e <= NTOK + E*127 (full) or re*CAP (rounds)
    size_t fixed_end = off;
    auto need = [&](size_t rows) { return fixed_end + rows * (size_t)(CDIM + DFF) * 2 + 4096; };
    int re;  // experts per round
    size_t rows;
    if (ws_size >= need(NTOK + E_NUM * 128)) { re = E_NUM; rows = NTOK + E_NUM * 128; }
    else if (ws_size >= need(2 * CAP))       { re = 2;     rows = 2 * CAP; }
    else                                     { re = 1;     rows = CAP; }
    u16* Xg = (u16*)alloc(rows * CDIM * 2);
    u16* Hb = (u16*)alloc(rows * DFF * 2);

    hipMemsetAsync(cnt, 0, (size_t)E_NUM * CNT_PAD * sizeof(int), stream);
    hipMemsetAsync(d_out, 0, (size_t)out_size * sizeof(float), stream);

    routing_kernel<<<NTOK / 16, 256, 0, stream>>>(x, noise, w_route, b_route,
                                                  w_noise, b_noise, top1, gate);
    build_lists_kernel<<<NTOK / 256, 256, 0, stream>>>(top1, cnt, list);
    transpose_cvt_kernel<<<dim3(DFF / 32, CDIM / 32, E_NUM), dim3(32, 8), 0, stream>>>(
        w1, W1t, CDIM, DFF);
    transpose_cvt_kernel<<<dim3(CDIM / 32, DFF / 32, E_NUM), dim3(32, 8), 0, stream>>>(
        w2, W2t, DFF, CDIM);

    for (int e0 = 0; e0 < E_NUM; e0 += re) {
        offsets_kernel<<<1, 64, 0, stream>>>(cnt, offs, e0, re);
        gather_kernel<<<dim3(CAP / 4, 1, re), 256, 0, stream>>>(
            x, list, cnt, offs, e0, Xg);
        gemm_kernel<CDIM, DFF, true><<<dim3(DFF / 128, CAP / 128, re), 256, 0, stream>>>(
            Xg, W1t, b1, Hb, nullptr, cnt, offs, e0, nullptr, nullptr);
        gemm_kernel<DFF, CDIM, false><<<dim3(CDIM / 128, CAP / 128, re), 256, 0, stream>>>(
            Hb, W2t, b2, nullptr, out, cnt, offs, e0, list, gate);
    }
}

// Round 5
// 356.482 us; speedup vs baseline: 2.8089x; 1.1830x over previous
//
#include <hip/hip_runtime.h>
#include <stdint.h>

#define E_NUM 8
#define CAP 8192
#define NTOK 32768
#define CDIM 384
#define DFF 1536
#define CNT_PAD 64  // ints between counters -> 256B, separate cache lines

typedef unsigned short u16;
typedef __attribute__((ext_vector_type(8))) short short8;
typedef __attribute__((ext_vector_type(4))) float f32x4;

__device__ inline u16 f2bf(float f) {
    uint32_t u = __builtin_bit_cast(uint32_t, f);
    u += 0x7fffu + ((u >> 16) & 1u);
    return (u16)(u >> 16);
}

__device__ inline void gload_lds16(const void* g, void* l) {
    __builtin_amdgcn_global_load_lds(
        (const __attribute__((address_space(1))) void*)(uintptr_t)g,
        (__attribute__((address_space(3))) void*)(uint32_t)(uintptr_t)l,
        16, 0, 0);
}

// DPP row-rotate reduction -> halves; finish with readlane(0)+readlane(32).
__device__ inline float rsum_to_halves(float v) {
    int s;
    s = __builtin_bit_cast(int, v);
    v += __builtin_bit_cast(float, __builtin_amdgcn_update_dpp(0, s, 0x121, 0xF, 0xF, false));
    s = __builtin_bit_cast(int, v);
    v += __builtin_bit_cast(float, __builtin_amdgcn_update_dpp(0, s, 0x122, 0xF, 0xF, false));
    s = __builtin_bit_cast(int, v);
    v += __builtin_bit_cast(float, __builtin_amdgcn_update_dpp(0, s, 0x124, 0xF, 0xF, false));
    s = __builtin_bit_cast(int, v);
    v += __builtin_bit_cast(float, __builtin_amdgcn_update_dpp(0, s, 0x128, 0xF, 0xF, false));
    s = __builtin_bit_cast(int, v);
    v += __builtin_bit_cast(float, __builtin_amdgcn_ds_swizzle(s, 0x401F));
    return v;
}

__device__ inline float lane_total(float v) {
    int s = __builtin_bit_cast(int, v);
    return __builtin_bit_cast(float, __builtin_amdgcn_readlane(s, 0)) +
           __builtin_bit_cast(float, __builtin_amdgcn_readlane(s, 32));
}

// ---------------- routing: weights in VGPRs, DPP reduce, no atomics ----------------
__global__ __launch_bounds__(256) void routing_kernel(
    const float* __restrict__ x, const float* __restrict__ noise,
    const float* __restrict__ w_route, const float* __restrict__ b_route,
    const float* __restrict__ w_noise, const float* __restrict__ b_noise,
    int* __restrict__ top1, float* __restrict__ gate)
{
    int lane = threadIdx.x & 63, w = threadIdx.x >> 6;
    float wr[6][8], wn[6][8];
#pragma unroll
    for (int i = 0; i < 6; ++i) {
        const float4* pr = (const float4*)(w_route + (size_t)(lane + 64 * i) * 8);
        const float4* pn = (const float4*)(w_noise + (size_t)(lane + 64 * i) * 8);
        float4 a = pr[0], b = pr[1], c = pn[0], d = pn[1];
        wr[i][0] = a.x; wr[i][1] = a.y; wr[i][2] = a.z; wr[i][3] = a.w;
        wr[i][4] = b.x; wr[i][5] = b.y; wr[i][6] = b.z; wr[i][7] = b.w;
        wn[i][0] = c.x; wn[i][1] = c.y; wn[i][2] = c.z; wn[i][3] = c.w;
        wn[i][4] = d.x; wn[i][5] = d.y; wn[i][6] = d.z; wn[i][7] = d.w;
    }
    float br[E_NUM], bn[E_NUM];
#pragma unroll
    for (int e = 0; e < E_NUM; ++e) { br[e] = b_route[e]; bn[e] = b_noise[e]; }

    int tbase = blockIdx.x * 16 + w * 4;
#pragma unroll
    for (int tt = 0; tt < 4; ++tt) {
        int t = tbase + tt;
        const float* xr = x + (size_t)t * CDIM;
        float xv[6];
#pragma unroll
        for (int i = 0; i < 6; ++i) xv[i] = xr[lane + i * 64];
        float ar[E_NUM], an[E_NUM];
#pragma unroll
        for (int e = 0; e < E_NUM; ++e) { ar[e] = 0.f; an[e] = 0.f; }
#pragma unroll
        for (int i = 0; i < 6; ++i)
#pragma unroll
            for (int e = 0; e < E_NUM; ++e) {
                ar[e] += xv[i] * wr[i][e];
                an[e] += xv[i] * wn[i][e];
            }
        float nz[E_NUM];
        const float* np = noise + (size_t)t * E_NUM;
#pragma unroll
        for (int e = 0; e < E_NUM; ++e) {
            float sr = lane_total(rsum_to_halves(ar[e])) + br[e];
            float sn = lane_total(rsum_to_halves(an[e])) + bn[e];
            float sp = fmaxf(sn, 0.f) + log1pf(expf(-fabsf(sn)));
            nz[e] = sr + np[e] * sp;
        }
        float v1 = -1e30f; int i1 = 0;
#pragma unroll
        for (int e = 0; e < E_NUM; ++e) if (nz[e] > v1) { v1 = nz[e]; i1 = e; }
        float v2 = -1e30f;
#pragma unroll
        for (int e = 0; e < E_NUM; ++e) if (e != i1 && nz[e] > v2) v2 = nz[e];
        if (lane == 0) {
            gate[t] = 1.f / (1.f + expf(v2 - v1));
            top1[t] = i1;
        }
    }
}

// ---------------- ballot-aggregated list build ----------------
__global__ __launch_bounds__(256) void build_lists_kernel(
    const int* __restrict__ top1, int* __restrict__ cnt, int* __restrict__ list)
{
    int t = blockIdx.x * 256 + threadIdx.x;
    int lane = threadIdx.x & 63;
    int e1 = top1[t];
#pragma unroll
    for (int e = 0; e < E_NUM; ++e) {
        unsigned long long m = __ballot(e1 == e);
        if (m == 0) continue;
        int c = __popcll(m);
        int leader = __ffsll((long long)m) - 1;
        int base = 0;
        if (lane == leader) base = atomicAdd(&cnt[e * CNT_PAD], c);
        base = __shfl(base, leader);
        if (e1 == e) {
            int pos = base + __popcll(m & ((1ull << lane) - 1ull));
            if (pos < CAP) list[e * CAP + pos] = t;
        }
    }
}

// ---------------- packed-row offsets ----------------
__global__ void offsets_kernel(const int* __restrict__ cnt, int* __restrict__ offs)
{
    if (threadIdx.x == 0 && blockIdx.x == 0) {
        int o = 0;
        for (int e = 0; e < E_NUM; ++e) {
            offs[e] = o;
            int n = min(cnt[e * CNT_PAD], CAP);
            o += (n + 127) & ~127;
        }
    }
}

// ------------- transpose + fp32->bf16 convert: in (R,S) -> out (S,R) -------------
__global__ __launch_bounds__(256) void transpose_cvt_kernel(
    const float* __restrict__ in, u16* __restrict__ out, int R, int S)
{
    __shared__ float tile[32][33];
    size_t eoff = (size_t)blockIdx.z * R * S;
    const float* ip = in + eoff;
    u16* op = out + eoff;
    int c0 = blockIdx.x * 32, r0 = blockIdx.y * 32;
    int tx = threadIdx.x, ty = threadIdx.y;
#pragma unroll
    for (int i = ty; i < 32; i += 8)
        tile[i][tx] = ip[(size_t)(r0 + i) * S + (c0 + tx)];
    __syncthreads();
#pragma unroll
    for (int i = ty; i < 32; i += 8)
        op[(size_t)(c0 + i) * R + (r0 + tx)] = f2bf(tile[tx][i]);
}

// ------------- gather x rows -> bf16 into packed layout, zero-pad to 128 -------------
__global__ __launch_bounds__(256) void gather_kernel(
    const float* __restrict__ x, const int* __restrict__ list,
    const int* __restrict__ cnt, const int* __restrict__ offs,
    u16* __restrict__ Xg)
{
    int e = blockIdx.z;
    const int* le = list + (size_t)e * CAP;
    int n = min(cnt[e * CNT_PAD], CAP);
    int w = threadIdx.x >> 6, lane = threadIdx.x & 63;
    int row = blockIdx.x * 4 + w;
    int pad = (n + 127) & ~127;
    if (row >= pad) return;
    u16* orow = Xg + (size_t)(offs[e] + row) * CDIM;
    if (row < n) {
        const float* xr = x + (size_t)le[row] * CDIM;
#pragma unroll
        for (int i = 0; i < CDIM / 64; ++i) orow[lane + i * 64] = f2bf(xr[lane + i * 64]);
    } else {
#pragma unroll
        for (int i = 0; i < CDIM / 64; ++i) orow[lane + i * 64] = 0;
    }
}

// ------------- bf16 MFMA GEMM, 128x128 tile, BK=64, XCD swizzle, XOR-bank-swizzled LDS ---
// 1D grid = NT*512 blocks. xcd=bid&7, slot=bid>>3: consecutive same-XCD slots
// share one A M-tile (all NT N-tiles) -> A served from that XCD's L2.
// LDS tiles store 16B group g of row r at physical group g^(r&7): read addr
// offset is lane-constant, banks fully spread (R4: 4.77M conflicts).
template <int KD, int ND, bool FFN1>
__global__ __launch_bounds__(256, 4) void gemm_kernel(
    const u16* __restrict__ A, const u16* __restrict__ Bt,
    const float* __restrict__ bias, u16* __restrict__ H, float* __restrict__ Out,
    const int* __restrict__ cnt, const int* __restrict__ offs,
    const int* __restrict__ list, const float* __restrict__ gate)
{
    constexpr int NT = ND / 128;
    int bid = blockIdx.x;
    int xcd = bid & 7, slot = bid >> 3;
    int n_idx = slot % NT;
    int mglob = xcd + 8 * (slot / NT);     // 0..511
    int e = mglob >> 6;
    int m0 = (mglob & 63) * 128;
    int n_e = min(cnt[e * CNT_PAD], CAP);
    int pad_e = (n_e + 127) & ~127;
    if (m0 >= pad_e) return;
    int base = offs[e];
    const u16* Ae = A + (size_t)(base + m0) * KD;
    const u16* Be = Bt + ((size_t)e * ND + (size_t)n_idx * 128) * KD;

    __shared__ __align__(16) u16 As[128 * 64];
    __shared__ __align__(16) u16 Bs[128 * 64];

    int tid = threadIdx.x;
    int w = tid >> 6, lane = tid & 63;
    int quad = lane >> 4, l15 = lane & 15;
    int wr = w & 1, wc = w >> 1;

    // staging: inst i covers rows i*32 + (tid>>3), group tid&7 (physical),
    // sourced from global group (tid&7)^((tid>>3)&7) -> lane-constant column.
    int srow = tid >> 3;
    int gcol = ((tid & 7) ^ ((tid >> 3) & 7)) * 8;

    f32x4 acc[4][4];
    f32x4 zero = {0.f, 0.f, 0.f, 0.f};
#pragma unroll
    for (int a = 0; a < 4; ++a)
#pragma unroll
        for (int b = 0; b < 4; ++b) acc[a][b] = zero;

    for (int kb = 0; kb < KD / 64; ++kb) {
#pragma unroll
        for (int i = 0; i < 4; ++i) {
            int row = i * 32 + srow;
            gload_lds16(Ae + (size_t)row * KD + kb * 64 + gcol, &As[i * 2048 + tid * 8]);
            gload_lds16(Be + (size_t)row * KD + kb * 64 + gcol, &Bs[i * 2048 + tid * 8]);
        }
        __syncthreads();
#pragma unroll
        for (int h = 0; h < 2; ++h) {
            int pga = (((h * 4 + quad) ^ (l15 & 7))) * 8;  // lane-constant per h
            short8 af[4], bf[4];
#pragma unroll
            for (int t = 0; t < 4; ++t) {
                af[t] = *(const short8*)&As[(wr * 64 + t * 16 + l15) * 64 + pga];
                bf[t] = *(const short8*)&Bs[(wc * 64 + t * 16 + l15) * 64 + pga];
            }
#pragma unroll
            for (int mt = 0; mt < 4; ++mt)
#pragma unroll
                for (int nt = 0; nt < 4; ++nt)
                    acc[mt][nt] = __builtin_amdgcn_mfma_f32_16x16x32_bf16(
                        af[mt], bf[nt], acc[mt][nt], 0, 0, 0);
        }
        __syncthreads();
    }

    int n0 = n_idx * 128;
    if (FFN1) {
        u16* He = H + (size_t)(base + m0) * ND;
#pragma unroll
        for (int mt = 0; mt < 4; ++mt) {
            int rowL = wr * 64 + mt * 16 + quad * 4;
#pragma unroll
            for (int nt = 0; nt < 4; ++nt) {
                int col = n0 + wc * 64 + nt * 16 + l15;
                float b = bias[(size_t)e * ND + col];
#pragma unroll
                for (int r = 0; r < 4; ++r) {
                    float v = acc[mt][nt][r] + b;
                    v = fmaxf(v, 0.f);
                    v = v * v;
                    He[(size_t)(rowL + r) * ND + col] = f2bf(v);
                }
            }
        }
    } else {
#pragma unroll
        for (int mt = 0; mt < 4; ++mt) {
            int rowL = wr * 64 + mt * 16 + quad * 4;
#pragma unroll
            for (int r = 0; r < 4; ++r) {
                int rr = m0 + rowL + r;
                if (rr < n_e) {
                    int tok = list[(size_t)e * CAP + rr];
                    float g = gate[tok];
#pragma unroll
                    for (int nt = 0; nt < 4; ++nt) {
                        int col = n0 + wc * 64 + nt * 16 + l15;
                        float v = acc[mt][nt][r] + bias[(size_t)e * ND + col];
                        Out[(size_t)tok * CDIM + col] = v * g;
                    }
                }
            }
        }
    }
}

extern "C" void kernel_launch(void* const* d_in, const int* in_sizes, int n_in,
                              void* d_out, int out_size, void* d_ws, size_t ws_size,
                              hipStream_t stream)
{
    const float* x       = (const float*)d_in[0];
    const float* noise   = (const float*)d_in[1];
    const float* w_route = (const float*)d_in[2];
    const float* b_route = (const float*)d_in[3];
    const float* w_noise = (const float*)d_in[4];
    const float* b_noise = (const float*)d_in[5];
    const float* w1      = (const float*)d_in[6];
    const float* b1      = (const float*)d_in[7];
    const float* w2      = (const float*)d_in[8];
    const float* b2      = (const float*)d_in[9];
    float* out = (float*)d_out;

    char* ws = (char*)d_ws;
    size_t off = 0;
    auto alloc = [&](size_t bytes) {
        char* p = ws + off;
        off += (bytes + 255) & ~(size_t)255;
        return p;
    };
    int*   cnt  = (int*)alloc((size_t)E_NUM * CNT_PAD * sizeof(int));
    int*   top1 = (int*)alloc((size_t)NTOK * sizeof(int));
    int*   list = (int*)alloc((size_t)E_NUM * CAP * sizeof(int));
    float* gate = (float*)alloc((size_t)NTOK * sizeof(float));
    int*   offs = (int*)alloc((size_t)(E_NUM + 1) * sizeof(int));
    u16*   W1t  = (u16*)alloc((size_t)E_NUM * DFF * CDIM * 2);
    u16*   W2t  = (u16*)alloc((size_t)E_NUM * CDIM * DFF * 2);

    size_t rows = NTOK + E_NUM * 128;  // packed-row bound
    u16* Xg = (u16*)alloc(rows * CDIM * 2);
    u16* Hb = (u16*)alloc(rows * DFF * 2);

    hipMemsetAsync(cnt, 0, (size_t)E_NUM * CNT_PAD * sizeof(int), stream);
    hipMemsetAsync(d_out, 0, (size_t)out_size * sizeof(float), stream);

    routing_kernel<<<NTOK / 16, 256, 0, stream>>>(x, noise, w_route, b_route,
                                                  w_noise, b_noise, top1, gate);
    build_lists_kernel<<<NTOK / 256, 256, 0, stream>>>(top1, cnt, list);
    transpose_cvt_kernel<<<dim3(DFF / 32, CDIM / 32, E_NUM), dim3(32, 8), 0, stream>>>(
        w1, W1t, CDIM, DFF);
    transpose_cvt_kernel<<<dim3(CDIM / 32, DFF / 32, E_NUM), dim3(32, 8), 0, stream>>>(
        w2, W2t, DFF, CDIM);
    offsets_kernel<<<1, 64, 0, stream>>>(cnt, offs);
    gather_kernel<<<dim3(CAP / 4, 1, E_NUM), 256, 0, stream>>>(x, list, cnt, offs, Xg);

    gemm_kernel<CDIM, DFF, true><<<dim3((DFF / 128) * 512), 256, 0, stream>>>(
        Xg, W1t, b1, Hb, nullptr, cnt, offs, nullptr, nullptr);
    gemm_kernel<DFF, CDIM, false><<<dim3((CDIM / 128) * 512), 256, 0, stream>>>(
        Hb, W2t, b2, nullptr, out, cnt, offs, list, gate);
}

// Round 6
// 313.575 us; speedup vs baseline: 3.1933x; 1.1368x over previous
//
#include <hip/hip_runtime.h>
#include <stdint.h>

#define E_NUM 8
#define CAP 8192
#define NTOK 32768
#define CDIM 384
#define DFF 1536
#define CNT_PAD 64  // ints between counters -> 256B, separate cache lines

typedef unsigned short u16;
typedef __attribute__((ext_vector_type(8))) short short8;
typedef __attribute__((ext_vector_type(4))) float f32x4;

__device__ inline u16 f2bf(float f) {
    uint32_t u = __builtin_bit_cast(uint32_t, f);
    u += 0x7fffu + ((u >> 16) & 1u);
    return (u16)(u >> 16);
}

__device__ inline void gload_lds16(const void* g, void* l) {
    __builtin_amdgcn_global_load_lds(
        (const __attribute__((address_space(1))) void*)(uintptr_t)g,
        (__attribute__((address_space(3))) void*)(uint32_t)(uintptr_t)l,
        16, 0, 0);
}

// DPP row-rotate reduction -> halves; finish with readlane(0)+readlane(32).
__device__ inline float rsum_to_halves(float v) {
    int s;
    s = __builtin_bit_cast(int, v);
    v += __builtin_bit_cast(float, __builtin_amdgcn_update_dpp(0, s, 0x121, 0xF, 0xF, false));
    s = __builtin_bit_cast(int, v);
    v += __builtin_bit_cast(float, __builtin_amdgcn_update_dpp(0, s, 0x122, 0xF, 0xF, false));
    s = __builtin_bit_cast(int, v);
    v += __builtin_bit_cast(float, __builtin_amdgcn_update_dpp(0, s, 0x124, 0xF, 0xF, false));
    s = __builtin_bit_cast(int, v);
    v += __builtin_bit_cast(float, __builtin_amdgcn_update_dpp(0, s, 0x128, 0xF, 0xF, false));
    s = __builtin_bit_cast(int, v);
    v += __builtin_bit_cast(float, __builtin_amdgcn_ds_swizzle(s, 0x401F));
    return v;
}

__device__ inline float lane_total(float v) {
    int s = __builtin_bit_cast(int, v);
    return __builtin_bit_cast(float, __builtin_amdgcn_readlane(s, 0)) +
           __builtin_bit_cast(float, __builtin_amdgcn_readlane(s, 32));
}

// ---------------- routing: weights in VGPRs, DPP reduce, fast transcendentals --------
// R5 post-mortem: VGPR=68 < the 96 floats of weights -> compiler sank weight loads
// into the token loop (L1 re-fetch per token) and libm expf/log1pf burned ~300
// VALU instrs/token. Fix: __launch_bounds__(256,1) lifts the VGPR cap so float4
// weight quads stay resident; __expf/__logf use hw v_exp/v_log (~2ulp, harmless
// vs fp32 dot reorder noise).
__global__ __launch_bounds__(256, 1) void routing_kernel(
    const float* __restrict__ x, const float* __restrict__ noise,
    const float* __restrict__ w_route, const float* __restrict__ b_route,
    const float* __restrict__ w_noise, const float* __restrict__ b_noise,
    int* __restrict__ top1, float* __restrict__ gate)
{
    int lane = threadIdx.x & 63, w = threadIdx.x >> 6;
    // wr4[2i+j] = w_route[(lane+64i)*8 + 4j ..], 32B/lane contiguous -> coalesced
    float4 wr4[12], wn4[12];
#pragma unroll
    for (int i = 0; i < 6; ++i) {
        const float4* pr = (const float4*)(w_route + (size_t)(lane + 64 * i) * 8);
        const float4* pn = (const float4*)(w_noise + (size_t)(lane + 64 * i) * 8);
        wr4[2 * i] = pr[0]; wr4[2 * i + 1] = pr[1];
        wn4[2 * i] = pn[0]; wn4[2 * i + 1] = pn[1];
    }
    float br[E_NUM], bn[E_NUM];
#pragma unroll
    for (int e = 0; e < E_NUM; ++e) { br[e] = b_route[e]; bn[e] = b_noise[e]; }

    int tbase = blockIdx.x * 16 + w * 4;
#pragma unroll
    for (int tt = 0; tt < 4; ++tt) {
        int t = tbase + tt;
        const float* xr = x + (size_t)t * CDIM;
        float xv[6];
#pragma unroll
        for (int i = 0; i < 6; ++i) xv[i] = xr[lane + i * 64];
        float ar[E_NUM], an[E_NUM];
#pragma unroll
        for (int e = 0; e < E_NUM; ++e) { ar[e] = 0.f; an[e] = 0.f; }
#pragma unroll
        for (int i = 0; i < 6; ++i) {
            float4 r0 = wr4[2 * i], r1 = wr4[2 * i + 1];
            float4 n0 = wn4[2 * i], n1 = wn4[2 * i + 1];
            float xi = xv[i];
            ar[0] += xi * r0.x; ar[1] += xi * r0.y; ar[2] += xi * r0.z; ar[3] += xi * r0.w;
            ar[4] += xi * r1.x; ar[5] += xi * r1.y; ar[6] += xi * r1.z; ar[7] += xi * r1.w;
            an[0] += xi * n0.x; an[1] += xi * n0.y; an[2] += xi * n0.z; an[3] += xi * n0.w;
            an[4] += xi * n1.x; an[5] += xi * n1.y; an[6] += xi * n1.z; an[7] += xi * n1.w;
        }
        float nz[E_NUM];
        const float* np = noise + (size_t)t * E_NUM;
#pragma unroll
        for (int e = 0; e < E_NUM; ++e) {
            float sr = lane_total(rsum_to_halves(ar[e])) + br[e];
            float sn = lane_total(rsum_to_halves(an[e])) + bn[e];
            float sp = fmaxf(sn, 0.f) + __logf(1.f + __expf(-fabsf(sn)));
            nz[e] = sr + np[e] * sp;
        }
        float v1 = -1e30f; int i1 = 0;
#pragma unroll
        for (int e = 0; e < E_NUM; ++e) if (nz[e] > v1) { v1 = nz[e]; i1 = e; }
        float v2 = -1e30f;
#pragma unroll
        for (int e = 0; e < E_NUM; ++e) if (e != i1 && nz[e] > v2) v2 = nz[e];
        if (lane == 0) {
            gate[t] = 1.f / (1.f + __expf(v2 - v1));
            top1[t] = i1;
        }
    }
}

// ---------------- ballot-aggregated list build ----------------
__global__ __launch_bounds__(256) void build_lists_kernel(
    const int* __restrict__ top1, int* __restrict__ cnt, int* __restrict__ list)
{
    int t = blockIdx.x * 256 + threadIdx.x;
    int lane = threadIdx.x & 63;
    int e1 = top1[t];
#pragma unroll
    for (int e = 0; e < E_NUM; ++e) {
        unsigned long long m = __ballot(e1 == e);
        if (m == 0) continue;
        int c = __popcll(m);
        int leader = __ffsll((long long)m) - 1;
        int base = 0;
        if (lane == leader) base = atomicAdd(&cnt[e * CNT_PAD], c);
        base = __shfl(base, leader);
        if (e1 == e) {
            int pos = base + __popcll(m & ((1ull << lane) - 1ull));
            if (pos < CAP) list[e * CAP + pos] = t;
        }
    }
}

// ---------------- packed-row offsets ----------------
__global__ void offsets_kernel(const int* __restrict__ cnt, int* __restrict__ offs)
{
    if (threadIdx.x == 0 && blockIdx.x == 0) {
        int o = 0;
        for (int e = 0; e < E_NUM; ++e) {
            offs[e] = o;
            int n = min(cnt[e * CNT_PAD], CAP);
            o += (n + 127) & ~127;
        }
    }
}

// ------------- transpose + fp32->bf16 convert: in (R,S) -> out (S,R) -------------
__global__ __launch_bounds__(256) void transpose_cvt_kernel(
    const float* __restrict__ in, u16* __restrict__ out, int R, int S)
{
    __shared__ float tile[32][33];
    size_t eoff = (size_t)blockIdx.z * R * S;
    const float* ip = in + eoff;
    u16* op = out + eoff;
    int c0 = blockIdx.x * 32, r0 = blockIdx.y * 32;
    int tx = threadIdx.x, ty = threadIdx.y;
#pragma unroll
    for (int i = ty; i < 32; i += 8)
        tile[i][tx] = ip[(size_t)(r0 + i) * S + (c0 + tx)];
    __syncthreads();
#pragma unroll
    for (int i = ty; i < 32; i += 8)
        op[(size_t)(c0 + i) * R + (r0 + tx)] = f2bf(tile[tx][i]);
}

// ------------- gather x rows -> bf16 into packed layout, zero-pad to 128 -------------
__global__ __launch_bounds__(256) void gather_kernel(
    const float* __restrict__ x, const int* __restrict__ list,
    const int* __restrict__ cnt, const int* __restrict__ offs,
    u16* __restrict__ Xg)
{
    int e = blockIdx.z;
    const int* le = list + (size_t)e * CAP;
    int n = min(cnt[e * CNT_PAD], CAP);
    int w = threadIdx.x >> 6, lane = threadIdx.x & 63;
    int row = blockIdx.x * 4 + w;
    int pad = (n + 127) & ~127;
    if (row >= pad) return;
    u16* orow = Xg + (size_t)(offs[e] + row) * CDIM;
    if (row < n) {
        const float* xr = x + (size_t)le[row] * CDIM;
#pragma unroll
        for (int i = 0; i < CDIM / 64; ++i) orow[lane + i * 64] = f2bf(xr[lane + i * 64]);
    } else {
#pragma unroll
        for (int i = 0; i < CDIM / 64; ++i) orow[lane + i * 64] = 0;
    }
}

// ------------- bf16 MFMA GEMM, 128x128 tile, BK=64, XCD swizzle, XOR-bank-swizzled LDS ---
template <int KD, int ND, bool FFN1>
__global__ __launch_bounds__(256, 4) void gemm_kernel(
    const u16* __restrict__ A, const u16* __restrict__ Bt,
    const float* __restrict__ bias, u16* __restrict__ H, float* __restrict__ Out,
    const int* __restrict__ cnt, const int* __restrict__ offs,
    const int* __restrict__ list, const float* __restrict__ gate)
{
    constexpr int NT = ND / 128;
    int bid = blockIdx.x;
    int xcd = bid & 7, slot = bid >> 3;
    int n_idx = slot % NT;
    int mglob = xcd + 8 * (slot / NT);     // 0..511
    int e = mglob >> 6;
    int m0 = (mglob & 63) * 128;
    int n_e = min(cnt[e * CNT_PAD], CAP);
    int pad_e = (n_e + 127) & ~127;
    if (m0 >= pad_e) return;
    int base = offs[e];
    const u16* Ae = A + (size_t)(base + m0) * KD;
    const u16* Be = Bt + ((size_t)e * ND + (size_t)n_idx * 128) * KD;

    __shared__ __align__(16) u16 As[128 * 64];
    __shared__ __align__(16) u16 Bs[128 * 64];

    int tid = threadIdx.x;
    int w = tid >> 6, lane = tid & 63;
    int quad = lane >> 4, l15 = lane & 15;
    int wr = w & 1, wc = w >> 1;

    int srow = tid >> 3;
    int gcol = ((tid & 7) ^ ((tid >> 3) & 7)) * 8;

    f32x4 acc[4][4];
    f32x4 zero = {0.f, 0.f, 0.f, 0.f};
#pragma unroll
    for (int a = 0; a < 4; ++a)
#pragma unroll
        for (int b = 0; b < 4; ++b) acc[a][b] = zero;

    for (int kb = 0; kb < KD / 64; ++kb) {
#pragma unroll
        for (int i = 0; i < 4; ++i) {
            int row = i * 32 + srow;
            gload_lds16(Ae + (size_t)row * KD + kb * 64 + gcol, &As[i * 2048 + tid * 8]);
            gload_lds16(Be + (size_t)row * KD + kb * 64 + gcol, &Bs[i * 2048 + tid * 8]);
        }
        __syncthreads();
#pragma unroll
        for (int h = 0; h < 2; ++h) {
            int pga = (((h * 4 + quad) ^ (l15 & 7))) * 8;  // lane-constant per h
            short8 af[4], bf[4];
#pragma unroll
            for (int t = 0; t < 4; ++t) {
                af[t] = *(const short8*)&As[(wr * 64 + t * 16 + l15) * 64 + pga];
                bf[t] = *(const short8*)&Bs[(wc * 64 + t * 16 + l15) * 64 + pga];
            }
#pragma unroll
            for (int mt = 0; mt < 4; ++mt)
#pragma unroll
                for (int nt = 0; nt < 4; ++nt)
                    acc[mt][nt] = __builtin_amdgcn_mfma_f32_16x16x32_bf16(
                        af[mt], bf[nt], acc[mt][nt], 0, 0, 0);
        }
        __syncthreads();
    }

    int n0 = n_idx * 128;
    if (FFN1) {
        u16* He = H + (size_t)(base + m0) * ND;
#pragma unroll
        for (int mt = 0; mt < 4; ++mt) {
            int rowL = wr * 64 + mt * 16 + quad * 4;
#pragma unroll
            for (int nt = 0; nt < 4; ++nt) {
                int col = n0 + wc * 64 + nt * 16 + l15;
                float b = bias[(size_t)e * ND + col];
#pragma unroll
                for (int r = 0; r < 4; ++r) {
                    float v = acc[mt][nt][r] + b;
                    v = fmaxf(v, 0.f);
                    v = v * v;
                    He[(size_t)(rowL + r) * ND + col] = f2bf(v);
                }
            }
        }
    } else {
#pragma unroll
        for (int mt = 0; mt < 4; ++mt) {
            int rowL = wr * 64 + mt * 16 + quad * 4;
#pragma unroll
            for (int r = 0; r < 4; ++r) {
                int rr = m0 + rowL + r;
                if (rr < n_e) {
                    int tok = list[(size_t)e * CAP + rr];
                    float g = gate[tok];
#pragma unroll
                    for (int nt = 0; nt < 4; ++nt) {
                        int col = n0 + wc * 64 + nt * 16 + l15;
                        float v = acc[mt][nt][r] + bias[(size_t)e * ND + col];
                        Out[(size_t)tok * CDIM + col] = v * g;
                    }
                }
            }
        }
    }
}

extern "C" void kernel_launch(void* const* d_in, const int* in_sizes, int n_in,
                              void* d_out, int out_size, void* d_ws, size_t ws_size,
                              hipStream_t stream)
{
    const float* x       = (const float*)d_in[0];
    const float* noise   = (const float*)d_in[1];
    const float* w_route = (const float*)d_in[2];
    const float* b_route = (const float*)d_in[3];
    const float* w_noise = (const float*)d_in[4];
    const float* b_noise = (const float*)d_in[5];
    const float* w1      = (const float*)d_in[6];
    const float* b1      = (const float*)d_in[7];
    const float* w2      = (const float*)d_in[8];
    const float* b2      = (const float*)d_in[9];
    float* out = (float*)d_out;

    char* ws = (char*)d_ws;
    size_t off = 0;
    auto alloc = [&](size_t bytes) {
        char* p = ws + off;
        off += (bytes + 255) & ~(size_t)255;
        return p;
    };
    int*   cnt  = (int*)alloc((size_t)E_NUM * CNT_PAD * sizeof(int));
    int*   top1 = (int*)alloc((size_t)NTOK * sizeof(int));
    int*   list = (int*)alloc((size_t)E_NUM * CAP * sizeof(int));
    float* gate = (float*)alloc((size_t)NTOK * sizeof(float));
    int*   offs = (int*)alloc((size_t)(E_NUM + 1) * sizeof(int));
    u16*   W1t  = (u16*)alloc((size_t)E_NUM * DFF * CDIM * 2);
    u16*   W2t  = (u16*)alloc((size_t)E_NUM * CDIM * DFF * 2);

    size_t rows = NTOK + E_NUM * 128;  // packed-row bound
    u16* Xg = (u16*)alloc(rows * CDIM * 2);
    u16* Hb = (u16*)alloc(rows * DFF * 2);

    hipMemsetAsync(cnt, 0, (size_t)E_NUM * CNT_PAD * sizeof(int), stream);
    hipMemsetAsync(d_out, 0, (size_t)out_size * sizeof(float), stream);

    routing_kernel<<<NTOK / 16, 256, 0, stream>>>(x, noise, w_route, b_route,
                                                  w_noise, b_noise, top1, gate);
    build_lists_kernel<<<NTOK / 256, 256, 0, stream>>>(top1, cnt, list);
    transpose_cvt_kernel<<<dim3(DFF / 32, CDIM / 32, E_NUM), dim3(32, 8), 0, stream>>>(
        w1, W1t, CDIM, DFF);
    transpose_cvt_kernel<<<dim3(CDIM / 32, DFF / 32, E_NUM), dim3(32, 8), 0, stream>>>(
        w2, W2t, DFF, CDIM);
    offsets_kernel<<<1, 64, 0, stream>>>(cnt, offs);
    gather_kernel<<<dim3(CAP / 4, 1, E_NUM), 256, 0, stream>>>(x, list, cnt, offs, Xg);

    gemm_kernel<CDIM, DFF, true><<<dim3((DFF / 128) * 512), 256, 0, stream>>>(
        Xg, W1t, b1, Hb, nullptr, cnt, offs, nullptr, nullptr);
    gemm_kernel<DFF, CDIM, false><<<dim3((CDIM / 128) * 512), 256, 0, stream>>>(
        Hb, W2t, b2, nullptr, out, cnt, offs, list, gate);
}